// Round 7
// baseline (173.789 us; speedup 1.0000x reference)
//
#include <hip/hip_runtime.h>
#include <hip/hip_bf16.h>

#define DIMS 64
#define BATCH 8
#define NCHUNK 4           // 64 dims / 16 dims per chunk; 3.2 MB slice fits 4 MB L2

// ---------------------------------------------------------------------------
// Kernel A: XWc = bf16(X @ W) in CHUNKED layout [chunk][node][16], and
// out = X @ W1 (fp32 residual). 64-row tile, W/W1/X^T in LDS, 4x4x2 register
// tile. NT hints reverted (round-6 regression).
// ---------------------------------------------------------------------------
__global__ __launch_bounds__(256) void gcn_gemm2(
    const float* __restrict__ X, const float* __restrict__ W,
    const float* __restrict__ W1, __hip_bfloat16* __restrict__ XWc,
    float* __restrict__ out, int N)
{
    __shared__ float Ws[64 * 64];
    __shared__ float W1s[64 * 64];
    __shared__ float Xs[64 * 68];

    const int t = threadIdx.x;

    for (int i = t; i < 1024; i += 256) {
        reinterpret_cast<float4*>(Ws)[i]  = reinterpret_cast<const float4*>(W)[i];
        reinterpret_cast<float4*>(W1s)[i] = reinterpret_cast<const float4*>(W1)[i];
    }

    const int row0 = blockIdx.x * 64;

    for (int i = t; i < 1024; i += 256) {
        const int r  = i >> 4;
        const int k4 = (i & 15) * 4;
        const int row = row0 + r;
        float4 v = make_float4(0.f, 0.f, 0.f, 0.f);
        if (row < N)
            v = reinterpret_cast<const float4*>(X)[(size_t)row * 16 + (i & 15)];
        Xs[(k4 + 0) * 68 + r] = v.x;
        Xs[(k4 + 1) * 68 + r] = v.y;
        Xs[(k4 + 2) * 68 + r] = v.z;
        Xs[(k4 + 3) * 68 + r] = v.w;
    }
    __syncthreads();

    const int dg = t & 15;   // dims [4*dg, 4*dg+4)
    const int rg = t >> 4;   // rows [4*rg, 4*rg+4)

    float4 acc[4];
    float4 acc1[4];
    #pragma unroll
    for (int r = 0; r < 4; ++r) {
        acc[r]  = make_float4(0.f, 0.f, 0.f, 0.f);
        acc1[r] = make_float4(0.f, 0.f, 0.f, 0.f);
    }

    #pragma unroll 4
    for (int k = 0; k < 64; ++k) {
        const float4 x4 = *reinterpret_cast<const float4*>(&Xs[k * 68 + rg * 4]);
        const float4 w  = *reinterpret_cast<const float4*>(&Ws[k * 64 + dg * 4]);
        const float4 w1 = *reinterpret_cast<const float4*>(&W1s[k * 64 + dg * 4]);
        const float xr[4] = {x4.x, x4.y, x4.z, x4.w};
        #pragma unroll
        for (int r = 0; r < 4; ++r) {
            acc[r].x  += xr[r] * w.x;  acc[r].y  += xr[r] * w.y;
            acc[r].z  += xr[r] * w.z;  acc[r].w  += xr[r] * w.w;
            acc1[r].x += xr[r] * w1.x; acc1[r].y += xr[r] * w1.y;
            acc1[r].z += xr[r] * w1.z; acc1[r].w += xr[r] * w1.w;
        }
    }

    // chunk layout: dims [4dg,4dg+4) live in chunk c = dg>>2, slot (dg&3)
    const int c    = dg >> 2;
    const int slot = dg & 3;
    #pragma unroll
    for (int r = 0; r < 4; ++r) {
        const int row = row0 + rg * 4 + r;
        if (row < N) {
            reinterpret_cast<float4*>(out)[(size_t)row * 16 + dg] = acc1[r];
            uint2 pk;
            __hip_bfloat16* ph = reinterpret_cast<__hip_bfloat16*>(&pk);
            ph[0] = __float2bfloat16(acc[r].x);
            ph[1] = __float2bfloat16(acc[r].y);
            ph[2] = __float2bfloat16(acc[r].z);
            ph[3] = __float2bfloat16(acc[r].w);
            // XWc[c][row][4*slot .. 4*slot+4)  (uint2 = 4 bf16)
            reinterpret_cast<uint2*>(XWc)[((size_t)c * (N + 1) + row) * 4 + slot] = pk;
        }
    }
}

// ---------------------------------------------------------------------------
// Kernel R: row_ptr from sorted rows; zero the 4 per-chunk sentinel rows.
// ---------------------------------------------------------------------------
__global__ __launch_bounds__(256) void build_row_ptr(
    const int* __restrict__ rows, int* __restrict__ ptr,
    __hip_bfloat16* __restrict__ XWc, int E, int N)
{
    const int e = blockIdx.x * 256 + threadIdx.x;
    if (blockIdx.x == 0 && threadIdx.x < 32) {
        const int c = threadIdx.x >> 3;          // chunk
        const int w = threadIdx.x & 7;           // dword within 32-B row
        reinterpret_cast<uint32_t*>(XWc)[((size_t)c * (N + 1) + N) * 8 + w] = 0u;
    }
    if (e >= E) return;
    const int r1 = rows[e];
    const int r0 = (e == 0) ? -1 : rows[e - 1];
    for (int r = r0 + 1; r <= r1; ++r) ptr[r] = e;
    if (e == E - 1) {
        for (int r = r1 + 1; r <= N; ++r) ptr[r] = E;
    }
}

// ---------------------------------------------------------------------------
// Kernel B: CSR aggregation, dim-chunked for L2 residency.
//  - chunk = blockIdx & 3  -> with round-robin block->XCD mapping, each XCD's
//    4 MB L2 holds one 3.2 MB chunk slice of XWc (gathers ~all L2-hit).
//  - wave = 32 rows; 2 lanes per row; lane half h reads dims [8h,8h+8) of the
//    chunk as one uint4 (16 B): one wave instr = 32 edges' slices.
//  - branchless sentinel row (node N) for tail slots; no atomics: RMW on top
//    of the X@W1 residual.
// ---------------------------------------------------------------------------
__global__ __launch_bounds__(256) void gcn_csr(
    const __hip_bfloat16* __restrict__ XWc, const float* __restrict__ dd1,
    const int* __restrict__ ptr, const int* __restrict__ cols,
    float* __restrict__ out, int N, int E)
{
    const int chunk = blockIdx.x & 3;
    const int rblk  = blockIdx.x >> 2;
    const int wv    = threadIdx.x >> 6;
    const int lane  = threadIdx.x & 63;
    const int r     = lane >> 1;           // row slot 0..31
    const int h     = lane & 1;            // 16-B half of the 32-B chunk row

    const int row = (rblk * 4 + wv) * 32 + r;
    int p0 = 0, p1 = 0;
    if (row < N) { p0 = ptr[row]; p1 = ptr[row + 1]; }

    // base of this chunk's [node][16] table (incl. sentinel node N)
    const __hip_bfloat16* tbl = XWc + ((size_t)chunk * (N + 1)) * 16;

    float acc[8];
    #pragma unroll
    for (int k = 0; k < 8; ++k) acc[k] = 0.f;

    for (int e = p0; __any(e < p1); e += BATCH) {
        uint4 raw[BATCH];
        #pragma unroll
        for (int j = 0; j < BATCH; ++j) {
            const int ee = e + j;
            const int es = (ee < E) ? ee : (E - 1);   // safe index read
            const int cl = cols[es];
            const int c  = (ee < p1) ? cl : N;        // sentinel -> zeros
            raw[j] = *reinterpret_cast<const uint4*>(
                reinterpret_cast<const char*>(tbl) + (size_t)c * 32 + h * 16);
        }
        #pragma unroll
        for (int j = 0; j < BATCH; ++j) {
            const uint32_t w0 = raw[j].x, w1 = raw[j].y, w2 = raw[j].z, w3 = raw[j].w;
            acc[0] += __uint_as_float(w0 << 16);
            acc[1] += __uint_as_float(w0 & 0xffff0000u);
            acc[2] += __uint_as_float(w1 << 16);
            acc[3] += __uint_as_float(w1 & 0xffff0000u);
            acc[4] += __uint_as_float(w2 << 16);
            acc[5] += __uint_as_float(w2 & 0xffff0000u);
            acc[6] += __uint_as_float(w3 << 16);
            acc[7] += __uint_as_float(w3 & 0xffff0000u);
        }
    }

    if (row < N) {
        const float s = 1.0f / dd1[row];
        // out[row][16*chunk + 8h .. +8): two contiguous float4 (32 B/lane;
        // 2-lane group covers 64 B contiguous)
        float4* po = reinterpret_cast<float4*>(
            out + (size_t)row * DIMS + chunk * 16 + h * 8);
        float4 o0 = po[0];
        float4 o1 = po[1];
        o0.x += acc[0] * s;  o0.y += acc[1] * s;
        o0.z += acc[2] * s;  o0.w += acc[3] * s;
        o1.x += acc[4] * s;  o1.y += acc[5] * s;
        o1.z += acc[6] * s;  o1.w += acc[7] * s;
        po[0] = o0;
        po[1] = o1;
    }
}

// ---------------------------------------------------------------------------
extern "C" void kernel_launch(void* const* d_in, const int* in_sizes, int n_in,
                              void* d_out, int out_size, void* d_ws, size_t ws_size,
                              hipStream_t stream) {
    const float* X   = (const float*)d_in[0];
    const float* W   = (const float*)d_in[1];
    const float* W1  = (const float*)d_in[2];
    const float* dd1 = (const float*)d_in[3];
    const int* rows  = (const int*)d_in[4];
    const int* cols  = (const int*)d_in[5];

    const int N = in_sizes[3];
    const int E = in_sizes[4];

    // ws layout: XWc 4 chunks x (N+1) nodes x 16 bf16 | row_ptr
    char* wsp = (char*)d_ws;
    __hip_bfloat16* XWc = (__hip_bfloat16*)wsp;
    size_t off = (((size_t)NCHUNK * (N + 1) * 16 * sizeof(__hip_bfloat16)) + 255) & ~(size_t)255;
    int* row_ptr = (int*)(wsp + off);

    float* out = (float*)d_out;

    // R: row_ptr + zero per-chunk sentinel rows
    hipLaunchKernelGGL(build_row_ptr, dim3((E + 255) / 256), dim3(256), 0, stream,
                       rows, row_ptr, XWc, E, N);

    // A: XWc = bf16(X@W) chunked, out = X@W1
    hipLaunchKernelGGL(gcn_gemm2, dim3((N + 63) / 64), dim3(256), 0, stream,
                       X, W, W1, XWc, out, N);

    // B: out[row] += (sum_{e in row} XWc[:, cols[e]]) / dd1[row]
    // block = 4 waves x 32 rows = 128 rows, x4 chunk copies in low bits of
    // blockIdx (XCD-affine: blockIdx % 8 -> XCD, & 3 -> chunk)
    const int rblks  = (N + 127) / 128;
    hipLaunchKernelGGL(gcn_csr, dim3(rblks * NCHUNK), dim3(256), 0, stream,
                       XWc, dd1, row_ptr, cols, out, N, E);
}

// Round 8
// 148.332 us; speedup vs baseline: 1.1716x; 1.1716x over previous
//
#include <hip/hip_runtime.h>
#include <hip/hip_bf16.h>

#define DIMS 64
#define BATCH 8

// sign-extend byte b (0..3) of 32-bit word w  -> v_bfe_i32
#define SEXT8(w, b) ((int)((w) << (24 - 8 * (b))) >> 24)

// ---------------------------------------------------------------------------
// Kernel A: Q = int8(X @ W) with per-row scale (rowmax/127), out = X @ W1.
// 64-row tile, W/W1/X^T in LDS, 4x4x2 register tile (round-5 structure).
// Row absmax via 16-lane xor-shuffle across the dg lanes holding the row.
// ---------------------------------------------------------------------------
__global__ __launch_bounds__(256) void gcn_gemm2(
    const float* __restrict__ X, const float* __restrict__ W,
    const float* __restrict__ W1, signed char* __restrict__ Q,
    float* __restrict__ scales, float* __restrict__ out, int N)
{
    __shared__ float Ws[64 * 64];
    __shared__ float W1s[64 * 64];
    __shared__ float Xs[64 * 68];

    const int t = threadIdx.x;

    for (int i = t; i < 1024; i += 256) {
        reinterpret_cast<float4*>(Ws)[i]  = reinterpret_cast<const float4*>(W)[i];
        reinterpret_cast<float4*>(W1s)[i] = reinterpret_cast<const float4*>(W1)[i];
    }

    const int row0 = blockIdx.x * 64;

    for (int i = t; i < 1024; i += 256) {
        const int r  = i >> 4;
        const int k4 = (i & 15) * 4;
        const int row = row0 + r;
        float4 v = make_float4(0.f, 0.f, 0.f, 0.f);
        if (row < N)
            v = reinterpret_cast<const float4*>(X)[(size_t)row * 16 + (i & 15)];
        Xs[(k4 + 0) * 68 + r] = v.x;
        Xs[(k4 + 1) * 68 + r] = v.y;
        Xs[(k4 + 2) * 68 + r] = v.z;
        Xs[(k4 + 3) * 68 + r] = v.w;
    }
    __syncthreads();

    const int dg = t & 15;   // dims [4*dg, 4*dg+4)
    const int rg = t >> 4;   // rows [4*rg, 4*rg+4)

    float4 acc[4];
    float4 acc1[4];
    #pragma unroll
    for (int r = 0; r < 4; ++r) {
        acc[r]  = make_float4(0.f, 0.f, 0.f, 0.f);
        acc1[r] = make_float4(0.f, 0.f, 0.f, 0.f);
    }

    #pragma unroll 4
    for (int k = 0; k < 64; ++k) {
        const float4 x4 = *reinterpret_cast<const float4*>(&Xs[k * 68 + rg * 4]);
        const float4 w  = *reinterpret_cast<const float4*>(&Ws[k * 64 + dg * 4]);
        const float4 w1 = *reinterpret_cast<const float4*>(&W1s[k * 64 + dg * 4]);
        const float xr[4] = {x4.x, x4.y, x4.z, x4.w};
        #pragma unroll
        for (int r = 0; r < 4; ++r) {
            acc[r].x  += xr[r] * w.x;  acc[r].y  += xr[r] * w.y;
            acc[r].z  += xr[r] * w.z;  acc[r].w  += xr[r] * w.w;
            acc1[r].x += xr[r] * w1.x; acc1[r].y += xr[r] * w1.y;
            acc1[r].z += xr[r] * w1.z; acc1[r].w += xr[r] * w1.w;
        }
    }

    #pragma unroll
    for (int r = 0; r < 4; ++r) {
        const int row = row0 + rg * 4 + r;

        // row absmax over the 16 dg-lanes (lanes (rg&3)*16 .. +15 of this wave)
        float m = fmaxf(fmaxf(fabsf(acc[r].x), fabsf(acc[r].y)),
                        fmaxf(fabsf(acc[r].z), fabsf(acc[r].w)));
        #pragma unroll
        for (int mk = 1; mk < 16; mk <<= 1)
            m = fmaxf(m, __shfl_xor(m, mk));

        if (row < N) {
            reinterpret_cast<float4*>(out)[(size_t)row * 16 + dg] = acc1[r];

            const float inv = (m > 0.f) ? 127.0f / m : 0.f;
            const int qx = (int)rintf(acc[r].x * inv);
            const int qy = (int)rintf(acc[r].y * inv);
            const int qz = (int)rintf(acc[r].z * inv);
            const int qw = (int)rintf(acc[r].w * inv);
            const uint32_t pk = (uint32_t)(qx & 0xff) |
                                ((uint32_t)(qy & 0xff) << 8) |
                                ((uint32_t)(qz & 0xff) << 16) |
                                ((uint32_t)(qw & 0xff) << 24);
            reinterpret_cast<uint32_t*>(Q)[(size_t)row * 16 + dg] = pk;
            if (dg == 0) scales[row] = m * (1.0f / 127.0f);
        }
    }
}

// ---------------------------------------------------------------------------
// Kernel R: row_ptr from sorted rows; zero sentinel Q row + sentinel scale.
// ---------------------------------------------------------------------------
__global__ __launch_bounds__(256) void build_row_ptr(
    const int* __restrict__ rows, int* __restrict__ ptr,
    signed char* __restrict__ Q, float* __restrict__ scales, int E, int N)
{
    const int e = blockIdx.x * 256 + threadIdx.x;
    if (blockIdx.x == 0 && threadIdx.x < 16)
        reinterpret_cast<uint32_t*>(Q)[(size_t)N * 16 + threadIdx.x] = 0u;
    if (blockIdx.x == 0 && threadIdx.x == 16) scales[N] = 0.f;
    if (e >= E) return;
    const int r1 = rows[e];
    const int r0 = (e == 0) ? -1 : rows[e - 1];
    for (int r = r0 + 1; r <= r1; ++r) ptr[r] = e;
    if (e == E - 1) {
        for (int r = r1 + 1; r <= N; ++r) ptr[r] = E;
    }
}

// ---------------------------------------------------------------------------
// Kernel B: CSR row-centric aggregation over int8 rows (round-5 structure).
// One wave = 8 rows; 8-lane group per row; lane d = dims [8d,8d+8) as 8 int8
// (uint2, 8 B). Per-node fp32 scale gathered alongside (scales table 400 KB,
// L2-hot). Branchless via sentinel row N (q=0, scale=0). No atomics: RMW on
// top of the X@W1 residual. fp32 accumulate: bfe + cvt + fmac per element.
// ---------------------------------------------------------------------------
__global__ __launch_bounds__(256) void gcn_csr(
    const signed char* __restrict__ Q, const float* __restrict__ scales,
    const float* __restrict__ dd1, const int* __restrict__ ptr,
    const int* __restrict__ cols, float* __restrict__ out, int N, int E)
{
    const int t    = blockIdx.x * 256 + threadIdx.x;
    const int wave = t >> 6;
    const int lane = threadIdx.x & 63;
    const int g    = lane >> 3;     // group 0..7  -> row
    const int d    = lane & 7;      // dim block   -> dims [8d, 8d+8)

    const int row = wave * 8 + g;
    int p0 = 0, p1 = 0;
    if (row < N) { p0 = ptr[row]; p1 = ptr[row + 1]; }

    float acc[8];
    #pragma unroll
    for (int k = 0; k < 8; ++k) acc[k] = 0.f;

    for (int e = p0; __any(e < p1); e += BATCH) {
        uint2  qv[BATCH];
        float  sv[BATCH];
        #pragma unroll
        for (int j = 0; j < BATCH; ++j) {
            const int ee = e + j;
            const int es = (ee < E) ? ee : (E - 1);   // safe index read
            const int cl = cols[es];
            const int c  = (ee < p1) ? cl : N;        // sentinel -> zeros
            qv[j] = *reinterpret_cast<const uint2*>(Q + ((size_t)c << 6) + (d << 3));
            sv[j] = scales[c];
        }
        #pragma unroll
        for (int j = 0; j < BATCH; ++j) {
            const uint32_t w0 = qv[j].x, w1 = qv[j].y;
            const float sc = sv[j];
            acc[0] += (float)SEXT8(w0, 0) * sc;
            acc[1] += (float)SEXT8(w0, 1) * sc;
            acc[2] += (float)SEXT8(w0, 2) * sc;
            acc[3] += (float)SEXT8(w0, 3) * sc;
            acc[4] += (float)SEXT8(w1, 0) * sc;
            acc[5] += (float)SEXT8(w1, 1) * sc;
            acc[6] += (float)SEXT8(w1, 2) * sc;
            acc[7] += (float)SEXT8(w1, 3) * sc;
        }
    }

    if (row < N) {
        const float s = 1.0f / dd1[row];
        float4* po = reinterpret_cast<float4*>(out + (size_t)row * DIMS + d * 8);
        float4 o0 = po[0];
        float4 o1 = po[1];
        o0.x += acc[0] * s;  o0.y += acc[1] * s;
        o0.z += acc[2] * s;  o0.w += acc[3] * s;
        o1.x += acc[4] * s;  o1.y += acc[5] * s;
        o1.z += acc[6] * s;  o1.w += acc[7] * s;
        po[0] = o0;
        po[1] = o1;
    }
}

// ---------------------------------------------------------------------------
extern "C" void kernel_launch(void* const* d_in, const int* in_sizes, int n_in,
                              void* d_out, int out_size, void* d_ws, size_t ws_size,
                              hipStream_t stream) {
    const float* X   = (const float*)d_in[0];
    const float* W   = (const float*)d_in[1];
    const float* W1  = (const float*)d_in[2];
    const float* dd1 = (const float*)d_in[3];
    const int* rows  = (const int*)d_in[4];
    const int* cols  = (const int*)d_in[5];

    const int N = in_sizes[3];
    const int E = in_sizes[4];

    // ws layout: Q (N+1 rows x 64 int8) | scales (N+1 fp32) | row_ptr (N+1)
    char* wsp = (char*)d_ws;
    signed char* Q = (signed char*)wsp;
    size_t off = (((size_t)(N + 1) * 64) + 255) & ~(size_t)255;
    float* scales = (float*)(wsp + off);
    off += (((size_t)(N + 1) * sizeof(float)) + 255) & ~(size_t)255;
    int* row_ptr = (int*)(wsp + off);

    float* out = (float*)d_out;

    // R: row_ptr + zero sentinel row/scale
    hipLaunchKernelGGL(build_row_ptr, dim3((E + 255) / 256), dim3(256), 0, stream,
                       rows, row_ptr, Q, scales, E, N);

    // A: Q,scales = int8(X@W), out = X@W1
    hipLaunchKernelGGL(gcn_gemm2, dim3((N + 63) / 64), dim3(256), 0, stream,
                       X, W, W1, Q, scales, out, N);

    // B: out[row] += (sum_{e in row} scales[c]*Q[c]) / dd1[row]
    const int waves  = (N + 7) / 8;
    const int blocks = (waves + 3) / 4;
    hipLaunchKernelGGL(gcn_csr, dim3(blocks), dim3(256), 0, stream,
                       Q, scales, dd1, row_ptr, cols, out, N, E);
}

// Round 9
// 135.931 us; speedup vs baseline: 1.2785x; 1.0912x over previous
//
#include <hip/hip_runtime.h>
#include <hip/hip_bf16.h>

#define DIMS 64
#define BATCH 8

typedef short  bf16x8 __attribute__((ext_vector_type(8)));
typedef float  f32x4v __attribute__((ext_vector_type(4)));

static __device__ __forceinline__ short f2bf(float f) {
    __hip_bfloat16 h = __float2bfloat16(f);
    return *reinterpret_cast<short*>(&h);
}

// ---------------------------------------------------------------------------
// Kernel A (MFMA): XWh = bf16(X@W), XW1h = bf16(X@W1), both in pi-permuted
// dim order: table position 4L+t  <->  natural col L+16t  (L=0..15, t=0..3).
// Wave = 16 rows x 64 cols; block = 4 waves = 64 rows. No LDS, no barriers.
//  - A-frag (mfma_f32_16x16x32_bf16): lane holds X[row0+ (lane&15)][k0+q*8..+8)
//    -> one float4x2 global load = 16 contiguous 128-B segments per wave.
//  - B-frags from W/W1 direct (16 KB, L2/L1-hot).
//  - C/D layout: col = ntile*16 + (lane&15), row = q*4 + reg.
// ---------------------------------------------------------------------------
__global__ __launch_bounds__(256) void gcn_gemm_mfma(
    const float* __restrict__ X, const float* __restrict__ W,
    const float* __restrict__ W1, __hip_bfloat16* __restrict__ XWh,
    __hip_bfloat16* __restrict__ XW1h, int N)
{
    const int w    = threadIdx.x >> 6;      // wave 0..3
    const int lane = threadIdx.x & 63;
    const int L    = lane & 15;
    const int q    = lane >> 4;

    const int row0 = blockIdx.x * 64 + w * 16;
    const int rowA = row0 + L;
    const int rowC = (rowA < N) ? rowA : (N - 1);   // clamped A-load row

    // B fragments: [mat][kh][ntile]; B[n=lane&15][k=q*8+j]
    bf16x8 bfrag[2][2][4];
    #pragma unroll
    for (int kh = 0; kh < 2; ++kh)
        #pragma unroll
        for (int nt = 0; nt < 4; ++nt)
            #pragma unroll
            for (int j = 0; j < 8; ++j) {
                const int k = kh * 32 + q * 8 + j;
                bfrag[0][kh][nt][j] = f2bf(W [k * 64 + nt * 16 + L]);
                bfrag[1][kh][nt][j] = f2bf(W1[k * 64 + nt * 16 + L]);
            }

    f32x4v acc[2][4];
    #pragma unroll
    for (int m = 0; m < 2; ++m)
        #pragma unroll
        for (int nt = 0; nt < 4; ++nt)
            acc[m][nt] = (f32x4v){0.f, 0.f, 0.f, 0.f};

    #pragma unroll
    for (int kh = 0; kh < 2; ++kh) {
        const float4 xa = reinterpret_cast<const float4*>(
            X + (size_t)rowC * 64 + kh * 32 + q * 8)[0];
        const float4 xb = reinterpret_cast<const float4*>(
            X + (size_t)rowC * 64 + kh * 32 + q * 8)[1];
        bf16x8 a;
        a[0] = f2bf(xa.x); a[1] = f2bf(xa.y); a[2] = f2bf(xa.z); a[3] = f2bf(xa.w);
        a[4] = f2bf(xb.x); a[5] = f2bf(xb.y); a[6] = f2bf(xb.z); a[7] = f2bf(xb.w);
        #pragma unroll
        for (int nt = 0; nt < 4; ++nt) {
            acc[0][nt] = __builtin_amdgcn_mfma_f32_16x16x32_bf16(
                a, bfrag[0][kh][nt], acc[0][nt], 0, 0, 0);
            acc[1][nt] = __builtin_amdgcn_mfma_f32_16x16x32_bf16(
                a, bfrag[1][kh][nt], acc[1][nt], 0, 0, 0);
        }
    }

    // Epilogue: lane packs its 4 n-tile values (cols L,L+16,L+32,L+48) of row
    // q*4+r into one 8-B store at pi-positions 4L..4L+3. 16 lanes/quad cover
    // the full 128-B row.
    #pragma unroll
    for (int r = 0; r < 4; ++r) {
        const int row = row0 + q * 4 + r;
        if (row < N) {
            ushort4 p0, p1;
            p0.x = (unsigned short)f2bf(acc[0][0][r]);
            p0.y = (unsigned short)f2bf(acc[0][1][r]);
            p0.z = (unsigned short)f2bf(acc[0][2][r]);
            p0.w = (unsigned short)f2bf(acc[0][3][r]);
            p1.x = (unsigned short)f2bf(acc[1][0][r]);
            p1.y = (unsigned short)f2bf(acc[1][1][r]);
            p1.z = (unsigned short)f2bf(acc[1][2][r]);
            p1.w = (unsigned short)f2bf(acc[1][3][r]);
            *reinterpret_cast<ushort4*>(XWh  + ((size_t)row << 6) + 4 * L) = p0;
            *reinterpret_cast<ushort4*>(XW1h + ((size_t)row << 6) + 4 * L) = p1;
        }
    }
}

// ---------------------------------------------------------------------------
// Kernel R: row_ptr from sorted rows; zero sentinel XWh row (node N).
// ---------------------------------------------------------------------------
__global__ __launch_bounds__(256) void build_row_ptr(
    const int* __restrict__ rows, int* __restrict__ ptr,
    __hip_bfloat16* __restrict__ XWh, int E, int N)
{
    const int e = blockIdx.x * 256 + threadIdx.x;
    if (blockIdx.x == 0 && threadIdx.x < 32)
        reinterpret_cast<uint32_t*>(XWh + ((size_t)N << 6))[threadIdx.x] = 0u;
    if (e >= E) return;
    const int r1 = rows[e];
    const int r0 = (e == 0) ? -1 : rows[e - 1];
    for (int r = r0 + 1; r <= r1; ++r) ptr[r] = e;
    if (e == E - 1) {
        for (int r = r1 + 1; r <= N; ++r) ptr[r] = E;
    }
}

// ---------------------------------------------------------------------------
// Kernel B: CSR row-centric aggregation (round-5 structure, bf16 rows).
// One wave = 8 rows; 8-lane group per row; lane d reads pi-positions
// [8d,8d+8) as one uint4 (16 B). Branchless via sentinel row N.
// Epilogue: out[row] = acc/dd1 + XW1h[row]  -- PURE STORE (no RMW read),
// un-permuting pi -> natural cols: acc[k] <-> col 2d + (k>>2) + 16*(k&3).
// ---------------------------------------------------------------------------
__global__ __launch_bounds__(256) void gcn_csr(
    const __hip_bfloat16* __restrict__ XWh, const __hip_bfloat16* __restrict__ XW1h,
    const float* __restrict__ dd1, const int* __restrict__ ptr,
    const int* __restrict__ cols, float* __restrict__ out, int N, int E)
{
    const int t    = blockIdx.x * 256 + threadIdx.x;
    const int wave = t >> 6;
    const int lane = threadIdx.x & 63;
    const int g    = lane >> 3;     // group 0..7  -> row
    const int d    = lane & 7;      // pi-dim block

    const int row = wave * 8 + g;
    int p0 = 0, p1 = 0;
    if (row < N) { p0 = ptr[row]; p1 = ptr[row + 1]; }

    float acc[8];
    #pragma unroll
    for (int k = 0; k < 8; ++k) acc[k] = 0.f;

    for (int e = p0; __any(e < p1); e += BATCH) {
        uint4 raw[BATCH];
        #pragma unroll
        for (int j = 0; j < BATCH; ++j) {
            const int ee = e + j;
            const int es = (ee < E) ? ee : (E - 1);   // safe index read
            const int cl = cols[es];
            const int c  = (ee < p1) ? cl : N;        // sentinel -> zeros
            raw[j] = *reinterpret_cast<const uint4*>(
                XWh + (((size_t)c) << 6) + (d << 3));
        }
        #pragma unroll
        for (int j = 0; j < BATCH; ++j) {
            const uint32_t w0 = raw[j].x, w1 = raw[j].y, w2 = raw[j].z, w3 = raw[j].w;
            acc[0] += __uint_as_float(w0 << 16);
            acc[1] += __uint_as_float(w0 & 0xffff0000u);
            acc[2] += __uint_as_float(w1 << 16);
            acc[3] += __uint_as_float(w1 & 0xffff0000u);
            acc[4] += __uint_as_float(w2 << 16);
            acc[5] += __uint_as_float(w2 & 0xffff0000u);
            acc[6] += __uint_as_float(w3 << 16);
            acc[7] += __uint_as_float(w3 & 0xffff0000u);
        }
    }

    if (row < N) {
        const float s = 1.0f / dd1[row];
        // residual slice, same pi-positions [8d, 8d+8)
        const uint4 rr = *reinterpret_cast<const uint4*>(
            XW1h + (((size_t)row) << 6) + (d << 3));
        float res[8];
        res[0] = __uint_as_float(rr.x << 16);
        res[1] = __uint_as_float(rr.x & 0xffff0000u);
        res[2] = __uint_as_float(rr.y << 16);
        res[3] = __uint_as_float(rr.y & 0xffff0000u);
        res[4] = __uint_as_float(rr.z << 16);
        res[5] = __uint_as_float(rr.z & 0xffff0000u);
        res[6] = __uint_as_float(rr.w << 16);
        res[7] = __uint_as_float(rr.w & 0xffff0000u);
        // natural col 2d + delta + 16t  <-  k = 4*delta + t
        #pragma unroll
        for (int tt = 0; tt < 4; ++tt) {
            float2 o;
            o.x = acc[tt]     * s + res[tt];        // delta=0
            o.y = acc[4 + tt] * s + res[4 + tt];    // delta=1
            *reinterpret_cast<float2*>(
                out + ((size_t)row << 6) + tt * 16 + d * 2) = o;
        }
    }
}

// ---------------------------------------------------------------------------
extern "C" void kernel_launch(void* const* d_in, const int* in_sizes, int n_in,
                              void* d_out, int out_size, void* d_ws, size_t ws_size,
                              hipStream_t stream) {
    const float* X   = (const float*)d_in[0];
    const float* W   = (const float*)d_in[1];
    const float* W1  = (const float*)d_in[2];
    const float* dd1 = (const float*)d_in[3];
    const int* rows  = (const int*)d_in[4];
    const int* cols  = (const int*)d_in[5];

    const int N = in_sizes[3];
    const int E = in_sizes[4];

    // ws: XWh (N+1 rows, pi-order) | XW1h (N rows, pi-order) | row_ptr (N+1)
    char* wsp = (char*)d_ws;
    __hip_bfloat16* XWh = (__hip_bfloat16*)wsp;
    size_t off = (((size_t)(N + 1) * DIMS * sizeof(__hip_bfloat16)) + 255) & ~(size_t)255;
    __hip_bfloat16* XW1h = (__hip_bfloat16*)(wsp + off);
    off += (((size_t)N * DIMS * sizeof(__hip_bfloat16)) + 255) & ~(size_t)255;
    int* row_ptr = (int*)(wsp + off);

    float* out = (float*)d_out;

    // R: row_ptr + zero sentinel row
    hipLaunchKernelGGL(build_row_ptr, dim3((E + 255) / 256), dim3(256), 0, stream,
                       rows, row_ptr, XWh, E, N);

    // A: XWh = bf16(X@W), XW1h = bf16(X@W1)  (MFMA)
    hipLaunchKernelGGL(gcn_gemm_mfma, dim3((N + 63) / 64), dim3(256), 0, stream,
                       X, W, W1, XWh, XW1h, N);

    // B: out[row] = (sum XWh[cols]) / dd1[row] + XW1h[row]
    const int waves  = (N + 7) / 8;
    const int blocks = (waves + 3) / 4;
    hipLaunchKernelGGL(gcn_csr, dim3(blocks), dim3(256), 0, stream,
                       XWh, XW1h, dd1, row_ptr, cols, out, N, E);
}

// Round 10
// 129.145 us; speedup vs baseline: 1.3457x; 1.0526x over previous
//
#include <hip/hip_runtime.h>
#include <hip/hip_bf16.h>

#define DIMS 64
#define BATCH 16

typedef short  bf16x8 __attribute__((ext_vector_type(8)));
typedef float  f32x4v __attribute__((ext_vector_type(4)));

static __device__ __forceinline__ short f2bf(float f) {
    __hip_bfloat16 h = __float2bfloat16(f);
    return *reinterpret_cast<short*>(&h);
}

// ---------------------------------------------------------------------------
// Kernel A+R fused: blocks [0, gemmBlocks) run the MFMA GEMM role (no LDS,
// so fusion is free); blocks [gemmBlocks, ...) build row_ptr from the sorted
// rows and zero the sentinel XWh row. Saves a dispatch and overlaps rptr's
// tiny blocks under the GEMM's memory time.
//
// GEMM role: XWh = bf16(X@W), XW1h = bf16(X@W1), pi-permuted dim order
// (pos 4L+t <-> col L+16t). Wave = 16 rows x 64 cols; block = 64 rows.
// C/D layout (verified r9, absmax 0.125): col = nt*16+(lane&15), row = q*4+reg.
// ---------------------------------------------------------------------------
__global__ __launch_bounds__(256) void gcn_pre(
    const float* __restrict__ X, const float* __restrict__ W,
    const float* __restrict__ W1, __hip_bfloat16* __restrict__ XWh,
    __hip_bfloat16* __restrict__ XW1h, const int* __restrict__ rows,
    int* __restrict__ ptr, int N, int E, int gemmBlocks)
{
    if (blockIdx.x >= gemmBlocks) {
        // ---- row_ptr role ----
        const int rb = blockIdx.x - gemmBlocks;
        if (rb == 0 && threadIdx.x < 32)
            reinterpret_cast<uint32_t*>(XWh + ((size_t)N << 6))[threadIdx.x] = 0u;
        const int e = rb * 256 + threadIdx.x;
        if (e >= E) return;
        const int r1 = rows[e];
        const int r0 = (e == 0) ? -1 : rows[e - 1];
        for (int r = r0 + 1; r <= r1; ++r) ptr[r] = e;
        if (e == E - 1) {
            for (int r = r1 + 1; r <= N; ++r) ptr[r] = E;
        }
        return;
    }

    // ---- GEMM role ----
    const int w    = threadIdx.x >> 6;      // wave 0..3
    const int lane = threadIdx.x & 63;
    const int L    = lane & 15;
    const int q    = lane >> 4;

    const int row0 = blockIdx.x * 64 + w * 16;
    const int rowA = row0 + L;
    const int rowC = (rowA < N) ? rowA : (N - 1);   // clamped A-load row

    // B fragments: [mat][kh][ntile]; B[n=lane&15][k=q*8+j]
    bf16x8 bfrag[2][2][4];
    #pragma unroll
    for (int kh = 0; kh < 2; ++kh)
        #pragma unroll
        for (int nt = 0; nt < 4; ++nt)
            #pragma unroll
            for (int j = 0; j < 8; ++j) {
                const int k = kh * 32 + q * 8 + j;
                bfrag[0][kh][nt][j] = f2bf(W [k * 64 + nt * 16 + L]);
                bfrag[1][kh][nt][j] = f2bf(W1[k * 64 + nt * 16 + L]);
            }

    f32x4v acc[2][4];
    #pragma unroll
    for (int m = 0; m < 2; ++m)
        #pragma unroll
        for (int nt = 0; nt < 4; ++nt)
            acc[m][nt] = (f32x4v){0.f, 0.f, 0.f, 0.f};

    #pragma unroll
    for (int kh = 0; kh < 2; ++kh) {
        const float4 xa = reinterpret_cast<const float4*>(
            X + (size_t)rowC * 64 + kh * 32 + q * 8)[0];
        const float4 xb = reinterpret_cast<const float4*>(
            X + (size_t)rowC * 64 + kh * 32 + q * 8)[1];
        bf16x8 a;
        a[0] = f2bf(xa.x); a[1] = f2bf(xa.y); a[2] = f2bf(xa.z); a[3] = f2bf(xa.w);
        a[4] = f2bf(xb.x); a[5] = f2bf(xb.y); a[6] = f2bf(xb.z); a[7] = f2bf(xb.w);
        #pragma unroll
        for (int nt = 0; nt < 4; ++nt) {
            acc[0][nt] = __builtin_amdgcn_mfma_f32_16x16x32_bf16(
                a, bfrag[0][kh][nt], acc[0][nt], 0, 0, 0);
            acc[1][nt] = __builtin_amdgcn_mfma_f32_16x16x32_bf16(
                a, bfrag[1][kh][nt], acc[1][nt], 0, 0, 0);
        }
    }

    #pragma unroll
    for (int r = 0; r < 4; ++r) {
        const int row = row0 + q * 4 + r;
        if (row < N) {
            ushort4 p0, p1;
            p0.x = (unsigned short)f2bf(acc[0][0][r]);
            p0.y = (unsigned short)f2bf(acc[0][1][r]);
            p0.z = (unsigned short)f2bf(acc[0][2][r]);
            p0.w = (unsigned short)f2bf(acc[0][3][r]);
            p1.x = (unsigned short)f2bf(acc[1][0][r]);
            p1.y = (unsigned short)f2bf(acc[1][1][r]);
            p1.z = (unsigned short)f2bf(acc[1][2][r]);
            p1.w = (unsigned short)f2bf(acc[1][3][r]);
            *reinterpret_cast<ushort4*>(XWh  + ((size_t)row << 6) + 4 * L) = p0;
            *reinterpret_cast<ushort4*>(XW1h + ((size_t)row << 6) + 4 * L) = p1;
        }
    }
}

// ---------------------------------------------------------------------------
// Kernel B: CSR row-centric aggregation (r9 structure, BATCH 16 for deeper
// per-wave miss queues). One wave = 8 rows; 8-lane group per row; lane d
// reads pi-positions [8d,8d+8) as one uint4. Branchless sentinel row N.
// Epilogue: out[row] = acc/dd1 + XW1h[row] -- pure store, un-permuting pi.
// ---------------------------------------------------------------------------
__global__ __launch_bounds__(256) void gcn_csr(
    const __hip_bfloat16* __restrict__ XWh, const __hip_bfloat16* __restrict__ XW1h,
    const float* __restrict__ dd1, const int* __restrict__ ptr,
    const int* __restrict__ cols, float* __restrict__ out, int N, int E)
{
    const int t    = blockIdx.x * 256 + threadIdx.x;
    const int wave = t >> 6;
    const int lane = threadIdx.x & 63;
    const int g    = lane >> 3;     // group 0..7  -> row
    const int d    = lane & 7;      // pi-dim block

    const int row = wave * 8 + g;
    int p0 = 0, p1 = 0;
    if (row < N) { p0 = ptr[row]; p1 = ptr[row + 1]; }

    float acc[8];
    #pragma unroll
    for (int k = 0; k < 8; ++k) acc[k] = 0.f;

    for (int e = p0; __any(e < p1); e += BATCH) {
        uint4 raw[BATCH];
        #pragma unroll
        for (int j = 0; j < BATCH; ++j) {
            const int ee = e + j;
            const int es = (ee < E) ? ee : (E - 1);   // safe index read
            const int cl = cols[es];
            const int c  = (ee < p1) ? cl : N;        // sentinel -> zeros
            raw[j] = *reinterpret_cast<const uint4*>(
                XWh + (((size_t)c) << 6) + (d << 3));
        }
        #pragma unroll
        for (int j = 0; j < BATCH; ++j) {
            const uint32_t w0 = raw[j].x, w1 = raw[j].y, w2 = raw[j].z, w3 = raw[j].w;
            acc[0] += __uint_as_float(w0 << 16);
            acc[1] += __uint_as_float(w0 & 0xffff0000u);
            acc[2] += __uint_as_float(w1 << 16);
            acc[3] += __uint_as_float(w1 & 0xffff0000u);
            acc[4] += __uint_as_float(w2 << 16);
            acc[5] += __uint_as_float(w2 & 0xffff0000u);
            acc[6] += __uint_as_float(w3 << 16);
            acc[7] += __uint_as_float(w3 & 0xffff0000u);
        }
    }

    if (row < N) {
        const float s = 1.0f / dd1[row];
        const uint4 rr = *reinterpret_cast<const uint4*>(
            XW1h + (((size_t)row) << 6) + (d << 3));
        float res[8];
        res[0] = __uint_as_float(rr.x << 16);
        res[1] = __uint_as_float(rr.x & 0xffff0000u);
        res[2] = __uint_as_float(rr.y << 16);
        res[3] = __uint_as_float(rr.y & 0xffff0000u);
        res[4] = __uint_as_float(rr.z << 16);
        res[5] = __uint_as_float(rr.z & 0xffff0000u);
        res[6] = __uint_as_float(rr.w << 16);
        res[7] = __uint_as_float(rr.w & 0xffff0000u);
        // natural col 2d + delta + 16t  <-  k = 4*delta + t
        #pragma unroll
        for (int tt = 0; tt < 4; ++tt) {
            float2 o;
            o.x = acc[tt]     * s + res[tt];        // delta=0
            o.y = acc[4 + tt] * s + res[4 + tt];    // delta=1
            *reinterpret_cast<float2*>(
                out + ((size_t)row << 6) + tt * 16 + d * 2) = o;
        }
    }
}

// ---------------------------------------------------------------------------
extern "C" void kernel_launch(void* const* d_in, const int* in_sizes, int n_in,
                              void* d_out, int out_size, void* d_ws, size_t ws_size,
                              hipStream_t stream) {
    const float* X   = (const float*)d_in[0];
    const float* W   = (const float*)d_in[1];
    const float* W1  = (const float*)d_in[2];
    const float* dd1 = (const float*)d_in[3];
    const int* rows  = (const int*)d_in[4];
    const int* cols  = (const int*)d_in[5];

    const int N = in_sizes[3];
    const int E = in_sizes[4];

    // ws: XWh (N+1 rows, pi-order) | XW1h (N rows, pi-order) | row_ptr (N+1)
    char* wsp = (char*)d_ws;
    __hip_bfloat16* XWh = (__hip_bfloat16*)wsp;
    size_t off = (((size_t)(N + 1) * DIMS * sizeof(__hip_bfloat16)) + 255) & ~(size_t)255;
    __hip_bfloat16* XW1h = (__hip_bfloat16*)(wsp + off);
    off += (((size_t)N * DIMS * sizeof(__hip_bfloat16)) + 255) & ~(size_t)255;
    int* row_ptr = (int*)(wsp + off);

    float* out = (float*)d_out;

    // A+R fused: GEMM role + row_ptr role in one launch
    const int gemmBlocks = (N + 63) / 64;
    const int rptrBlocks = (E + 255) / 256;
    hipLaunchKernelGGL(gcn_pre, dim3(gemmBlocks + rptrBlocks), dim3(256), 0, stream,
                       X, W, W1, XWh, XW1h, rows, row_ptr, N, E, gemmBlocks);

    // B: out[row] = (sum XWh[cols]) / dd1[row] + XW1h[row]
    const int waves  = (N + 7) / 8;
    const int blocks = (waves + 3) / 4;
    hipLaunchKernelGGL(gcn_csr, dim3(blocks), dim3(256), 0, stream,
                       XWh, XW1h, dd1, row_ptr, cols, out, N, E);
}